// Round 3
// baseline (288.916 us; speedup 1.0000x reference)
//
#include <hip/hip_runtime.h>

// PerformerAttention: B=4 H=16 S=4096 D=64, fp32.
//   q = relu(Q)+eps; k = (relu(K)+eps)*mask
//   kv[bh][d][e] = sum_s k[s][d]*v[s][e];  ksum[bh][d] = sum_s k[s][d]
//   out[s][e] = (sum_d q[s][d]*kv[d][e]) / (sum_d q[s][d]*ksum[d])
//
// R7: R6's depth-3 zero-staging pipeline FAILED correctness (absmax 5.5e-3):
// WAR race — round r's global_load_lds overwrites the slot consumed in round
// r-1 while that round's ds_reads may still be queued in the DS pipe (vmcnt
// orders the write's data, nothing ordered it vs prior READS of the slot).
// Fix: s_waitcnt lgkmcnt(0) at the top of every issuing round, BEFORE the
// async_cp16 pair -> all prior slot reads are register-captured before the
// overwrite is enqueued (ds_reads can't sink past the memory-clobber asm).
// Pipeline unchanged otherwise:
//   * K and V via global_load_lds into wave-private ring-4 of 4-row tiles
//     (2 KB/slot, 8 KB/wave); slot indices compile-time (unroll x4).
//   * round t issues t+3; s_waitcnt vmcnt(6)/round keeps 6 VMEM in flight.
//   * mask preloaded to LDS behind a vmcnt-draining __syncthreads().
//   * K preprocessing (relu*m + eps*m) at LDS-read time; ksum per-lane col.
// pa_reduce / pa_out / launcher unchanged (attribution).

namespace {
constexpr int kB = 4, kH = 16, kS = 4096, kD = 64;
constexpr int kBH = kB * kH;
constexpr float kEps = 0.001f;

constexpr int KVSZ = kD * kD;     // 4096 floats
constexpr int SEG  = KVSZ + kD;   // 4160 floats per partial segment (kv + ksum)
constexpr int F4PS = SEG / 4;     // 1040 float4 per segment
}

// async global->LDS, 16 B per lane; LDS dest = wave-uniform base + lane*16
__device__ __forceinline__ void async_cp16(const float* g, float* l) {
  __builtin_amdgcn_global_load_lds(
      (const __attribute__((address_space(1))) void*)g,
      (__attribute__((address_space(3))) void*)l, 16, 0, 0);
}

// ---------------- Pass 1: partial kv + ksum, one segment per BLOCK ---------
__global__ __launch_bounds__(256, 2)   // (256,4) caused a 64-VGPR spill disaster; do not re-add
void pa_kv_partial(const float* __restrict__ key, const float* __restrict__ value,
                   const float* __restrict__ mask, float* __restrict__ P, int ch1) {
  // 4 waves x ring-4 x (K 256f + V 256f) = 8192 floats; combine reuses [0..4096)
  __shared__ float smemU[8192];
  __shared__ float msk[512];         // block's mask slice (keeps loop free of other VMEM)
  __shared__ float ksm[256];         // per-wave ksum staging [wave][64]

  const int tid  = threadIdx.x;
  const int wid  = tid >> 6;
  const int lane = tid & 63;

  const int bh    = blockIdx.x / ch1;
  const int chunk = blockIdx.x - bh * ch1;
  const int b     = bh >> 4;                 // kH = 16
  const int rows  = kS / ch1;
  const int s0    = chunk * rows;
  const int rounds = rows >> 4;              // 16-row rounds (4 rows/wave), mult of 4

  const float* kg = key   + (size_t)bh * kS * kD;
  const float* vg = value + (size_t)bh * kS * kD;
  const float* mb = mask  + (size_t)b * kS;

  for (int i = tid; i < rows; i += 256) msk[i] = mb[s0 + i];
  __syncthreads();                           // drains vmcnt -> clean counter base

  float* const ring = smemU + wid * 2048;    // wave-private 8 KB ring
#define RK(Pp) (ring + (Pp) * 512)           // K slot: 4x64 floats, linear
#define RV(Pp) (ring + (Pp) * 512 + 256)     // V slot: 4x64 floats, linear

  const int ti = lane >> 3;                  // 0..7 (d rows 8*ti..)
  const int tj = lane & 7;                   // 0..7 (e cols 8*tj..)
  const int rw = wid * 4;                    // wave's row offset within a round

  float acc[8][8];
#pragma unroll
  for (int i = 0; i < 8; ++i)
#pragma unroll
    for (int j = 0; j < 8; ++j) acc[i][j] = 0.f;
  float ksacc = 0.f;                         // lane owns column d = lane

  // ---- prologue: issue rounds 0,1,2 into slots 0,1,2 (6 VMEM in flight) ----
  {
    const size_t g0 = (size_t)(s0 + rw) * kD + lane * 4;
    async_cp16(kg + g0, RK(0));
    async_cp16(vg + g0, RV(0));
    asm volatile("" ::: "memory");
    async_cp16(kg + g0 + 16 * kD, RK(1));
    async_cp16(vg + g0 + 16 * kD, RV(1));
    asm volatile("" ::: "memory");
    async_cp16(kg + g0 + 32 * kD, RK(2));
    async_cp16(vg + g0 + 32 * kD, RV(2));
    asm volatile("" ::: "memory");
  }

  // One round:
  //   [issue] lgkmcnt(0)  -- WAR guard: slot (P+3)&3 == (P-1)&3 was consumed
  //                          last round; its ds_reads must be complete before
  //                          we enqueue the overwriting global_load_lds.
  //           issue round r+3 into that slot (2 VMEM).
  //   vmcnt(WAITN)        -- steady state: 8 outstanding -> 6; round r landed.
  //   consume slot P (relu/eps/mask at read time, 64x8x8 FMA block).
#define PA_RND(Pp, RR, DO_ISSUE, WAITN)                                       \
  {                                                                           \
    if (DO_ISSUE) {                                                           \
      asm volatile("s_waitcnt lgkmcnt(0)" ::: "memory");                      \
      const size_t gi = (size_t)(s0 + ((RR) + 3) * 16 + rw) * kD + lane * 4;  \
      async_cp16(kg + gi, RK(((Pp) + 3) & 3));                                \
      async_cp16(vg + gi, RV(((Pp) + 3) & 3));                                \
    }                                                                         \
    asm volatile("s_waitcnt vmcnt(" #WAITN ")" ::: "memory");                 \
    const float* Ks = RK(Pp);                                                 \
    const float* Vs = RV(Pp);                                                 \
    const int rb = (RR) * 16 + rw;                                            \
    _Pragma("unroll")                                                         \
    for (int ss = 0; ss < 4; ++ss) {                                          \
      const float m  = msk[rb + ss];                                          \
      const float em = kEps * m;                                              \
      ksacc += fmaf(fmaxf(Ks[ss * 64 + lane], 0.f), m, em);                   \
      const float4 kf0 = *(const float4*)&Ks[ss * 64 + 8 * ti];               \
      const float4 kf1 = *(const float4*)&Ks[ss * 64 + 8 * ti + 4];           \
      const float4 vf0 = *(const float4*)&Vs[ss * 64 + 8 * tj];               \
      const float4 vf1 = *(const float4*)&Vs[ss * 64 + 8 * tj + 4];           \
      float ka[8];                                                            \
      ka[0] = fmaf(fmaxf(kf0.x, 0.f), m, em);                                 \
      ka[1] = fmaf(fmaxf(kf0.y, 0.f), m, em);                                 \
      ka[2] = fmaf(fmaxf(kf0.z, 0.f), m, em);                                 \
      ka[3] = fmaf(fmaxf(kf0.w, 0.f), m, em);                                 \
      ka[4] = fmaf(fmaxf(kf1.x, 0.f), m, em);                                 \
      ka[5] = fmaf(fmaxf(kf1.y, 0.f), m, em);                                 \
      ka[6] = fmaf(fmaxf(kf1.z, 0.f), m, em);                                 \
      ka[7] = fmaf(fmaxf(kf1.w, 0.f), m, em);                                 \
      const float va_[8] = {vf0.x, vf0.y, vf0.z, vf0.w,                       \
                            vf1.x, vf1.y, vf1.z, vf1.w};                      \
      _Pragma("unroll")                                                       \
      for (int i = 0; i < 8; ++i)                                             \
        _Pragma("unroll")                                                     \
        for (int j = 0; j < 8; ++j)                                           \
          acc[i][j] = fmaf(ka[i], va_[j], acc[i][j]);                         \
    }                                                                         \
  }

  // main: every round r <= rounds-5 issues r+3 (slots compile-time: t mult of 4)
  int t = 0;
  for (; t < rounds - 7; t += 4) {
    PA_RND(0, t + 0, true, 6)
    PA_RND(1, t + 1, true, 6)
    PA_RND(2, t + 2, true, 6)
    PA_RND(3, t + 3, true, 6)
  }
  // tail: t == rounds-4; first tail round issues rounds-1, then drain 4/2/0
  PA_RND(0, t + 0, true, 6)
  PA_RND(1, t + 1, false, 4)
  PA_RND(2, t + 2, false, 2)
  PA_RND(3, t + 3, false, 0)
#undef PA_RND
#undef RK
#undef RV

  // per-wave ksum: lane owns column d = lane (no shuffles needed)
  ksm[wid * 64 + lane] = ksacc;

  // block combine: wave w adds its 8x8 acc into smemU[0..4096) (permuted
  // layout: f4 slot j*64+lane = kv[8*(lane>>3)+(j>>1)][8*(lane&7)+4*(j&1)..])
#pragma unroll
  for (int w = 0; w < 4; ++w) {
    __syncthreads();
    if (wid == w) {
#pragma unroll
      for (int i = 0; i < 8; ++i)
#pragma unroll
        for (int jj = 0; jj < 2; ++jj) {
          const int j = i * 2 + jj;
          float4 o = make_float4(acc[i][jj * 4 + 0], acc[i][jj * 4 + 1],
                                 acc[i][jj * 4 + 2], acc[i][jj * 4 + 3]);
          float* p = &smemU[(size_t)(j * 64 + lane) * 4];
          if (w != 0) {
            const float4 prev = *(const float4*)p;
            o.x += prev.x; o.y += prev.y; o.z += prev.z; o.w += prev.w;
          }
          *(float4*)p = o;
        }
    }
  }
  __syncthreads();

  // cooperative coalesced store of the single block segment
  float* Pd = P + (size_t)blockIdx.x * SEG;
#pragma unroll
  for (int i = 0; i < 4; ++i) {
    const int idx = tid + 256 * i;
    *(float4*)&Pd[(size_t)idx * 4] = *(const float4*)&smemU[(size_t)idx * 4];
  }
  if (tid < kD)
    Pd[KVSZ + tid] = ksm[tid] + ksm[64 + tid] + ksm[128 + tid] + ksm[192 + tid];
}

// ---------------- Reduce: sum block partials, un-permute kv ----------------
__global__ __launch_bounds__(256)
void pa_reduce(const float* __restrict__ P, float* __restrict__ R, int nseg) {
  const int gid = blockIdx.x * 256 + threadIdx.x;
  if (gid >= kBH * F4PS) return;
  const int bh  = gid / F4PS;
  const int pos = gid - bh * F4PS;

  const float* base = P + (size_t)bh * nseg * SEG + (size_t)pos * 4;
  float ax = 0.f, ay = 0.f, az = 0.f, aw = 0.f;
  for (int c = 0; c < nseg; ++c) {
    const float4 t = *(const float4*)(base + (size_t)c * SEG);
    ax += t.x; ay += t.y; az += t.z; aw += t.w;
  }

  int dpos;
  if (pos < KVSZ / 4) {          // un-permute to natural [d][e]
    const int j  = pos >> 6, ln = pos & 63;
    const int d  = 8 * (ln >> 3) + (j >> 1);
    const int e4 = 2 * (ln & 7) + (j & 1);
    dpos = d * 16 + e4;
  } else {
    dpos = pos;                  // ksum already natural
  }
  *(float4*)&R[(size_t)bh * SEG + (size_t)dpos * 4] = make_float4(ax, ay, az, aw);
}

// ---------------- Pass 2: out = (q . kv) / (q . ksum) ----------------------
__global__ __launch_bounds__(256)
void pa_out(const float* __restrict__ query, const float* __restrict__ R,
            float* __restrict__ out) {
  __shared__ float ost[64 * 68];   // 64-row output staging, pad 68 (17 KiB)

  const int tid    = threadIdx.x;
  const int bh     = blockIdx.x >> 4;
  const int rowblk = blockIdx.x & 15;
  const int s      = rowblk * 256 + tid;

  const float* qrow = query + ((size_t)bh * kS + s) * kD;
  const float* Rb   = R + (size_t)bh * SEG;   // wave-uniform -> scalar loads

  float4 acc[16];
#pragma unroll
  for (int e = 0; e < 16; ++e) acc[e] = make_float4(0.f, 0.f, 0.f, 0.f);
  float den = 0.f;

#pragma unroll 4
  for (int d4 = 0; d4 < 16; ++d4) {
    const float4 qv = *(const float4*)(qrow + 4 * d4);
    const float qd[4] = {fmaxf(qv.x, 0.f) + kEps, fmaxf(qv.y, 0.f) + kEps,
                         fmaxf(qv.z, 0.f) + kEps, fmaxf(qv.w, 0.f) + kEps};
#pragma unroll
    for (int dd = 0; dd < 4; ++dd) {
      const int d = 4 * d4 + dd;
      den = fmaf(qd[dd], Rb[KVSZ + d], den);
      const float* kvr = Rb + d * 64;          // uniform row -> SGPR broadcast
#pragma unroll
      for (int e = 0; e < 16; ++e) {
        acc[e].x = fmaf(qd[dd], kvr[4 * e + 0], acc[e].x);
        acc[e].y = fmaf(qd[dd], kvr[4 * e + 1], acc[e].y);
        acc[e].z = fmaf(qd[dd], kvr[4 * e + 2], acc[e].z);
        acc[e].w = fmaf(qd[dd], kvr[4 * e + 3], acc[e].w);
      }
    }
  }

  const float inv = 1.0f / den;
#pragma unroll
  for (int e = 0; e < 16; ++e) {
    acc[e].x *= inv; acc[e].y *= inv; acc[e].z *= inv; acc[e].w *= inv;
  }

  // staged coalesced store: batch bb covers 64 rows written by wave bb
  float* ob = out + ((size_t)bh * kS + (size_t)rowblk * 256) * kD;
  const int wid = tid >> 6, l = tid & 63;
  for (int bb = 0; bb < 4; ++bb) {
    if (wid == bb) {
#pragma unroll
      for (int e = 0; e < 16; ++e) *(float4*)&ost[l * 68 + 4 * e] = acc[e];
    }
    __syncthreads();
#pragma unroll
    for (int jj = 0; jj < 4; ++jj) {
      const int g = tid + 256 * jj;
      const int r = g >> 4, c = g & 15;
      *(float4*)&ob[(size_t)(bb * 64 + r) * kD + 4 * c] =
          *(const float4*)&ost[r * 68 + 4 * c];
    }
    __syncthreads();
  }
}

extern "C" void kernel_launch(void* const* d_in, const int* in_sizes, int n_in,
                              void* d_out, int out_size, void* d_ws, size_t ws_size,
                              hipStream_t stream) {
  const float* query = (const float*)d_in[0];
  const float* key   = (const float*)d_in[1];
  const float* value = (const float*)d_in[2];
  const float* mask  = (const float*)d_in[3];
  float* outp = (float*)d_out;

  // CH1 = S-chunks per bh; ONE segment per block. Pick largest that fits ws.
  auto need = [](int ch1) -> size_t {
    return (size_t)(kBH * ch1 + kBH) * SEG * sizeof(float);
  };
  int CH1 = 8;                                  // 9.2 MB, known-safe floor
  if (ws_size >= need(16)) CH1 = 16;            // 18.1 MB, 1024 blocks (4/CU)

  float* P = (float*)d_ws;                      // kBH*CH1 segments
  float* R = P + (size_t)kBH * CH1 * SEG;       // kBH segments (natural layout)

  hipLaunchKernelGGL(pa_kv_partial, dim3(kBH * CH1), dim3(256), 0, stream,
                     key, value, mask, P, CH1);
  hipLaunchKernelGGL(pa_reduce, dim3((kBH * F4PS + 255) / 256), dim3(256), 0, stream,
                     P, R, CH1);
  hipLaunchKernelGGL(pa_out, dim3(kBH * 16), dim3(256), 0, stream,
                     query, R, outp);
}